// Round 7
// baseline (158.620 us; speedup 1.0000x reference)
//
#include <hip/hip_runtime.h>
#include <hip/hip_fp16.h>

typedef float fx4 __attribute__((ext_vector_type(4)));   // native vec for nontemporal builtins

// ---------------- bicubic helpers (A = -0.75, torch) ----------------
__device__ __forceinline__ float cc1(float x) {
    return (1.25f * x - 2.25f) * x * x + 1.0f;
}
__device__ __forceinline__ float cc2(float x) {
    return ((-0.75f * x + 3.75f) * x - 6.0f) * x + 3.0f;
}

__device__ __forceinline__ void axis64(int o, float w[4], int idx[4]) {
    float src = (float)o * 63.0f / 255.0f;
    float f = floorf(src);
    float t = src - f;
    w[0] = cc2(t + 1.0f);
    w[1] = cc1(t);
    w[2] = cc1(1.0f - t);
    w[3] = cc2(2.0f - t);
    int i0 = (int)f;
#pragma unroll
    for (int k = 0; k < 4; ++k) idx[k] = min(max(i0 - 1 + k, 0), 63);
}

// Flow-warped sample weights/taps for output pixel (i,j), batch b.
// Partial-OOB taps get weight 0; returns false iff the whole 4x4 footprint
// is outside the padded [0,306) domain (then ALL weights are 0).
__device__ __forceinline__ bool pixel_taps(const float* __restrict__ flow, int b,
                                           int i, int j,
                                           float wx[4], float wy[4],
                                           int xs[4], int ys[4]) {
    float wwy[4], wwx[4];
    int yi4[4], xi4[4];
    axis64(i, wwy, yi4);
    axis64(j, wwx, xi4);

    const float* fb = flow + (long)b * 2 * 4096;
    float fx = 0.f, fy = 0.f;
#pragma unroll
    for (int m = 0; m < 4; ++m) {
        const float* r0 = fb + yi4[m] * 64;
        float sx = 0.f, sy = 0.f;
#pragma unroll
        for (int n = 0; n < 4; ++n) {
            sx += wwx[n] * r0[xi4[n]];
            sy += wwx[n] * r0[4096 + xi4[n]];
        }
        fx += wwy[m] * sx;
        fy += wwy[m] * sy;
    }

    const float gx256 = -1.0f + 2.0f * (float)j / 255.0f;
    const float gy256 = -1.0f + 2.0f * (float)i / 255.0f;
    const float gx306 = -1.0f + 2.0f * (float)(j + 25) / 305.0f;
    const float gy306 = -1.0f + 2.0f * (float)(i + 25) / 305.0f;
    const float x = (fx - gx256 + gx306 + 1.0f) * 152.5f;
    const float y = (fy - gy256 + gy306 + 1.0f) * 152.5f;

    const float ixf = floorf(x), iyf = floorf(y);
    const float tx = x - ixf, ty = y - iyf;
    wx[0] = cc2(tx + 1.f); wx[1] = cc1(tx); wx[2] = cc1(1.f - tx); wx[3] = cc2(2.f - tx);
    wy[0] = cc2(ty + 1.f); wy[1] = cc1(ty); wy[2] = cc1(1.f - ty); wy[3] = cc2(2.f - ty);
    const int ix = (int)ixf, iy = (int)iyf;

    bool anyx = false, anyy = false;
#pragma unroll
    for (int n = 0; n < 4; ++n) {
        int xx = ix - 1 + n;
        bool vx = (xx >= 0) && (xx < 306);
        anyx |= vx;
        if (!vx) wx[n] = 0.f;
        xs[n] = min(max(xx - 25, 0), 255);

        int yy = iy - 1 + n;
        bool vy = (yy >= 0) && (yy < 306);
        anyy |= vy;
        if (!vy) wy[n] = 0.f;
        ys[n] = min(max(yy - 25, 0), 255);
    }
    return anyx && anyy;
}

// ------- Kernel A: [B,C,H,W] fp32 -> ws [B,H*W,C] fp16 ----------------------
// Input reads are non-temporal (streamed once, never reused) so they don't
// evict the freshly-written ws lines from L2. ws stores stay normal so each
// XCD's 4 MB batch slice is L2-resident when the gather starts.
__global__ __launch_bounds__(256) void transpose_clast_h_kernel(
    const float* __restrict__ inp, __half* __restrict__ ws)
{
    __shared__ float lds[32 * 260];
    const int blk = blockIdx.x;           // 2048
    const int b = blk & 7;                // XCD batch affinity
    const int p0 = (blk >> 3) << 8;       // 256-pixel tile
    const float* ib = inp + ((long)b << 21);
    const int tid = threadIdx.x;
    const int l = tid & 63;
    const int w = tid >> 6;

#pragma unroll
    for (int k = 0; k < 8; ++k) {
        const int c = (k << 2) + w;
        const fx4 v = __builtin_nontemporal_load(
            (const fx4*)(ib + ((long)c << 16) + p0 + (l << 2)));
        *(fx4*)&lds[c * 260 + (l << 2)] = v;
    }
    __syncthreads();

    // thread = one pixel: cvt 32 ch fp32->fp16, 64 B contiguous store
    __half* wb = ws + (((long)b << 16) + p0 + tid) * 32;
    __half2 h[16];
#pragma unroll
    for (int c = 0; c < 16; ++c) {
        float a = lds[(2 * c + 0) * 260 + tid];
        float bb = lds[(2 * c + 1) * 260 + tid];
        h[c] = __float22half2_rn(make_float2(a, bb));
    }
#pragma unroll
    for (int q = 0; q < 4; ++q)
        *(fx4*)(wb + (q << 3)) = *(fx4*)&h[q * 4];
}

// ------- Kernel B: gather fp16 taps, wave = 16 pixels x 4 lane-groups -------
// Out stores are non-temporal: out is write-once, so letting it allocate in
// L2 only evicts the ws lines we're gathering from (round-5 FETCH evidence).
__global__ __launch_bounds__(256) void gather_clast_h_kernel(
    const __half* __restrict__ ws,   // [B, 65536, 32] fp16
    const float* __restrict__ flow,  // [B, 2, 64, 64]
    float* __restrict__ out)         // [B, 32, 256, 256] fp32
{
    __shared__ float w_lds[16][64];
    __shared__ int   o_lds[16][64];

    const int tid = threadIdx.x;
    const int blk = blockIdx.x;      // 8192
    const int b = blk & 7;           // XCD batch affinity
    const int pidx0 = (blk >> 3) << 6;   // 64 pixels per block

    if (tid < 64) {
        const int pidx = pidx0 + tid;
        const int i = pidx >> 8, j = pidx & 255;
        float wx[4], wy[4];
        int xs[4], ys[4];
        const bool valid = pixel_taps(flow, b, i, j, wx, wy, xs, ys);
#pragma unroll
        for (int m = 0; m < 4; ++m)
#pragma unroll
            for (int n = 0; n < 4; ++n) {
                w_lds[m * 4 + n][tid] = wy[m] * wx[n];
                // offset in fp16 elements within the batch slice; fully-OOB
                // pixels collapse to offset 0 (weights are all 0 anyway)
                o_lds[m * 4 + n][tid] = valid ? ((ys[m] << 13) + (xs[n] << 5)) : 0;
            }
    }
    __syncthreads();

    const int lane = tid & 63;
    const int wv   = tid >> 6;               // wave 0..3
    const int pl   = (wv << 4) + (lane & 15); // local pixel 0..63
    const int g    = lane >> 4;               // channel group 0..3 (8 ch each)

    float wr[16];
    int   orr[16];
#pragma unroll
    for (int k = 0; k < 16; ++k) {
        wr[k]  = w_lds[k][pl];
        orr[k] = o_lds[k][pl];
    }

    const __half* baseh = ws + ((long)b << 21) + (g << 3);

    float acc[8];
#pragma unroll
    for (int k = 0; k < 8; ++k) acc[k] = 0.f;

#pragma unroll
    for (int k = 0; k < 16; ++k) {
        fx4 v = *(const fx4*)(baseh + orr[k]);   // 8 fp16 channels
        const __half2* h = (const __half2*)&v;
        const float w = wr[k];
#pragma unroll
        for (int m = 0; m < 4; ++m) {
            float2 f = __half22float2(h[m]);
            acc[2 * m + 0] += w * f.x;
            acc[2 * m + 1] += w * f.y;
        }
    }

    const int pidx = pidx0 + pl;
    float* op = out + ((long)b << 21) + ((long)(g << 3) << 16) + pidx;
#pragma unroll
    for (int k = 0; k < 8; ++k)
        __builtin_nontemporal_store(acc[k], op + ((long)k << 16));
}

// ---------------- Fallback if ws too small ----------------
__global__ __launch_bounds__(256) void warp_bicubic_fallback(
    const float* __restrict__ inp,
    const float* __restrict__ flow,
    float* __restrict__ out)
{
    const int j = threadIdx.x;
    const int i = blockIdx.x & 255;
    const int b = blockIdx.x >> 8;

    float wx[4], wy[4];
    int xs[4], ys[4];
    pixel_taps(flow, b, i, j, wx, wy, xs, ys);

    float* op = out + (long)b * 32 * 65536 + i * 256 + j;
    const float* ib = inp + (long)b * 32 * 65536;
#pragma unroll 2
    for (int c = 0; c < 32; ++c) {
        const float* s = ib + c * 65536;
        float acc = 0.f;
#pragma unroll
        for (int m = 0; m < 4; ++m) {
            float wm = wy[m];
            if (wm != 0.f) {
                const float* r = s + ys[m] * 256;
                acc += wm * (wx[0] * r[xs[0]] + wx[1] * r[xs[1]] +
                             wx[2] * r[xs[2]] + wx[3] * r[xs[3]]);
            }
        }
        op[c * 65536] = acc;
    }
}

extern "C" void kernel_launch(void* const* d_in, const int* in_sizes, int n_in,
                              void* d_out, int out_size, void* d_ws, size_t ws_size,
                              hipStream_t stream) {
    const float* inp  = (const float*)d_in[0];   // [8,32,256,256]
    const float* flow = (const float*)d_in[1];   // [8,2,64,64]
    float* out = (float*)d_out;

    const size_t need = (size_t)8 * 32 * 256 * 256 * sizeof(__half);  // 32 MiB
    if (ws_size >= need) {
        __half* ws = (__half*)d_ws;
        transpose_clast_h_kernel<<<dim3(2048), dim3(256), 0, stream>>>(inp, ws);
        gather_clast_h_kernel<<<dim3(8192), dim3(256), 0, stream>>>(ws, flow, out);
    } else {
        warp_bicubic_fallback<<<dim3(8 * 256), dim3(256), 0, stream>>>(inp, flow, out);
    }
}